// Round 6
// baseline (1098.732 us; speedup 1.0000x reference)
//
#include <hip/hip_runtime.h>
#include <stdint.h>

#define NBATCH 16384
#define TT     20
#define CC     256
#define LDK    264   // LDS row stride (bf16 elems)
#define NT     256   // 4 waves
#define BPB    16    // batches per block (grid = 1024 -> 4 blocks/CU wanted, 2 fit by LDS)

typedef __bf16 bf16x8 __attribute__((ext_vector_type(8)));
typedef float  f32x4  __attribute__((ext_vector_type(4)));

// lgkm-only barrier: make LDS writes visible WITHOUT draining in-flight global loads
// (compiler __syncthreads emits s_waitcnt vmcnt(0) which kills cross-barrier prefetch).
#define LGKM_BAR() do { asm volatile("s_waitcnt lgkmcnt(0)" ::: "memory"); \
                        __builtin_amdgcn_s_barrier(); } while (0)

// Active-column tables from tb_mask(T=20, win=3):
// t=0,1:{0,1,2}  t=2:{0,1,2,3}  t=3..15:{t,t+1}  t=16: uniform 1/20  t=17..19:{17,18,19}
__constant__ int8_t c_CNT[TT]     = {3,3,4,2,2,2,2,2,2,2,2,2,2,2,2,2,0,3,3,3};
__constant__ int8_t c_OFF[TT]     = {0,3,6,10,12,14,16,18,20,22,24,26,28,30,32,34,0,36,39,42};
__constant__ int8_t c_COLS[TT][4] = {
    {0,1,2,0},{0,1,2,0},{0,1,2,3},
    {3,4,0,0},{4,5,0,0},{5,6,0,0},{6,7,0,0},{7,8,0,0},{8,9,0,0},
    {9,10,0,0},{10,11,0,0},{11,12,0,0},{12,13,0,0},{13,14,0,0},
    {14,15,0,0},{15,16,0,0},{0,0,0,0},
    {17,18,19,0},{17,18,19,0},{17,18,19,0}};
__constant__ int8_t c_PT[45] = {0,0,0,1,1,1,2,2,2,2,3,3,4,4,5,5,6,6,7,7,8,8,9,9,
                                10,10,11,11,12,12,13,13,14,14,15,15,17,17,17,18,18,18,19,19,19};
__constant__ int8_t c_PS[45] = {0,1,2,0,1,2,0,1,2,3,3,4,4,5,5,6,6,7,7,8,8,9,9,10,
                                10,11,11,12,12,13,13,14,14,15,15,16,17,18,19,17,18,19,17,18,19};

__device__ __forceinline__ uint16_t f2bf(float f) {
    __bf16 b = (__bf16)f;
    return __builtin_bit_cast(uint16_t, b);
}
__device__ __forceinline__ uint32_t pk2(float a, float b) {
    return (uint32_t)f2bf(a) | ((uint32_t)f2bf(b) << 16);
}
__device__ __forceinline__ float bflo(uint32_t u) { return __builtin_bit_cast(float, u << 16); }
__device__ __forceinline__ float bfhi(uint32_t u) { return __builtin_bit_cast(float, u & 0xffff0000u); }

// prep1: mqkT[n][k] = sum_h Wk[h,n]*Wq[h,k] / 16 ;  wvb[n][k] = bf16(Wv[n][k])
__global__ void prep1_kernel(const float* __restrict__ Wq, const float* __restrict__ Wk,
                             const float* __restrict__ Wv, uint16_t* __restrict__ mqkT,
                             uint16_t* __restrict__ wvb) {
    const int n = blockIdx.x;
    const int k = threadIdx.x;
    float acc = 0.f;
    for (int h = 0; h < CC; ++h)
        acc = fmaf(Wk[h * CC + n], Wq[h * CC + k], acc);
    mqkT[n * CC + k] = f2bf(acc * 0.0625f);
    wvb[n * CC + k]  = f2bf(Wv[n * CC + k]);
}

// prep2: swizzle B^T tables into per-wave MFMA fragment order (one coalesced 1KB load per frag)
__global__ void prep2_kernel(const uint16_t* __restrict__ mqkT, const uint16_t* __restrict__ wvb,
                             uint16_t* __restrict__ BqS, uint16_t* __restrict__ BvS) {
    const int bid = blockIdx.x;          // 0..63 : m*32 + w*8 + kk
    const int m  = bid >> 5;
    const int w  = (bid >> 3) & 3;
    const int kk = bid & 7;
    const int ct   = threadIdx.x >> 6;
    const int lane = threadIdx.x & 63;
    const uint16_t* src = m ? wvb : mqkT;
    uint16_t*       dst = m ? BvS : BqS;
    const int n   = w * 64 + ct * 16 + (lane & 15);
    const int col = kk * 32 + ((lane >> 4) << 3);
    uint4 v = *(const uint4*)(src + n * CC + col);
    *(uint4*)(dst + ((size_t)((w * 32 + kk * 4 + ct) * 64 + lane) << 3)) = v;
}

// D layout (m89): col = lane&15, row = 4*(lane>>4)+j.  64-col wave panel at wcol.
__device__ __forceinline__ void storeD(uint16_t* __restrict__ sD, int wcol, int lane,
                                       f32x4 acc[2][4]) {
    const int drow = (lane >> 4) << 2;
    const int dcol = lane & 15;
#pragma unroll
    for (int rt = 0; rt < 2; ++rt)
#pragma unroll
        for (int ct = 0; ct < 4; ++ct)
#pragma unroll
            for (int j = 0; j < 4; ++j) {
                int row = rt * 16 + drow + j;
                if (row < TT)
                    sD[row * LDK + (wcol + ct * 16 + dcol)] = f2bf(acc[rt][ct][j]);
            }
}

__device__ __forceinline__ void acc8(float* o, uint4 uv, float wgt) {
    o[0] = fmaf(bflo(uv.x), wgt, o[0]);
    o[1] = fmaf(bfhi(uv.x), wgt, o[1]);
    o[2] = fmaf(bflo(uv.y), wgt, o[2]);
    o[3] = fmaf(bfhi(uv.y), wgt, o[3]);
    o[4] = fmaf(bflo(uv.z), wgt, o[4]);
    o[5] = fmaf(bfhi(uv.z), wgt, o[5]);
    o[6] = fmaf(bflo(uv.w), wgt, o[6]);
    o[7] = fmaf(bfhi(uv.w), wgt, o[7]);
}

__global__ __launch_bounds__(NT, 2)
void attn_main(const float* __restrict__ f1g, const float* __restrict__ f2g,
               const uint16_t* __restrict__ BqS, const uint16_t* __restrict__ BvS,
               float* __restrict__ outg) {
    __shared__ uint16_t sF1[2][TT * LDK];   // feat1 bf16 double-buffered
    __shared__ uint16_t sF2[2][TT * LDK];   // feat2 bf16 double-buffered
    __shared__ uint16_t sT1[TT * LDK];      // t1 = feat1*Mqk
    __shared__ uint16_t sV [TT * LDK];      // v  = feat2*Wv^T
    __shared__ float    s_sim[45];

    const int tid  = threadIdx.x;
    const int lane = tid & 63;
    const int w    = tid >> 6;             // wave owns 64 output cols
    const int lrow = lane & 15;
    const uint16_t* bq = BqS + ((size_t)w << 14);
    const uint16_t* bv = BvS + ((size_t)w << 14);
    const size_t blockBase = (size_t)blockIdx.x * BPB * TT * CC;

    const int r0 = lrow;
    const int r1 = (16 + lrow < TT) ? (16 + lrow) : (TT - 1);

    float4 p1[5], p2[5];

    // ---- prologue: stage batch 0 -> LDS buf 0 ----
    {
        const float* f1 = f1g + blockBase;
        const float* f2 = f2g + blockBase;
#pragma unroll
        for (int j = 0; j < 5; ++j) {
            int s = tid + (j << 8);
            p1[j] = *(const float4*)(f1 + (s << 2));
            p2[j] = *(const float4*)(f2 + (s << 2));
        }
#pragma unroll
        for (int j = 0; j < 5; ++j) {
            int s  = tid + (j << 8);
            int r  = s >> 6;
            int c4 = (s & 63) << 2;
            uint2 ua; ua.x = pk2(p1[j].x, p1[j].y); ua.y = pk2(p1[j].z, p1[j].w);
            uint2 ub; ub.x = pk2(p2[j].x, p2[j].y); ub.y = pk2(p2[j].z, p2[j].w);
            *(uint2*)&sF1[0][r * LDK + c4] = ua;
            *(uint2*)&sF2[0][r * LDK + c4] = ub;
        }
    }
    LGKM_BAR();

    for (int i = 0; i < BPB; ++i) {
        const int cur = i & 1, nxt = cur ^ 1;
        const bool hasNext = (i + 1 < BPB);

        // ---- phase A: issue prefetch (stays in flight across lgkm barriers) ----
        if (hasNext) {
            const float* f1n = f1g + blockBase + (size_t)(i + 1) * TT * CC;
            const float* f2n = f2g + blockBase + (size_t)(i + 1) * TT * CC;
#pragma unroll
            for (int j = 0; j < 5; ++j) {
                int s = tid + (j << 8);
                p1[j] = *(const float4*)(f1n + (s << 2));
                p2[j] = *(const float4*)(f2n + (s << 2));
            }
        }
        __builtin_amdgcn_sched_barrier(0);   // pin prefetch issue above GEMM

        // ---- GEMM1: t1 = feat1 * Mqk ----
        f32x4 acc[2][4];
#pragma unroll
        for (int p = 0; p < 2; ++p)
#pragma unroll
            for (int q = 0; q < 4; ++q)
                acc[p][q] = f32x4{0.f, 0.f, 0.f, 0.f};
        const uint16_t* A1 = sF1[cur];
        const uint16_t* A2 = sF2[cur];
#pragma unroll
        for (int kk = 0; kk < 8; ++kk) {
            const int ko = kk * 32 + ((lane >> 4) << 3);
            bf16x8 x0 = __builtin_bit_cast(bf16x8, *(const uint4*)(A1 + r0 * LDK + ko));
            bf16x8 x1 = __builtin_bit_cast(bf16x8, *(const uint4*)(A1 + r1 * LDK + ko));
            bf16x8 bf[4];
#pragma unroll
            for (int ct = 0; ct < 4; ++ct)
                bf[ct] = __builtin_bit_cast(bf16x8,
                    *(const uint4*)(bq + (((kk << 2) + ct) * 64 + lane) * 8));
#pragma unroll
            for (int ct = 0; ct < 4; ++ct) {
                acc[0][ct] = __builtin_amdgcn_mfma_f32_16x16x32_bf16(x0, bf[ct], acc[0][ct], 0, 0, 0);
                acc[1][ct] = __builtin_amdgcn_mfma_f32_16x16x32_bf16(x1, bf[ct], acc[1][ct], 0, 0, 0);
            }
        }
        storeD(sT1, w << 6, lane, acc);
        LGKM_BAR();   // B1: t1 visible; prefetch still in flight

        // ---- phase B: sim (45 dots x 4 thr x 64ch) + GEMM2: v = feat2*Wv^T ----
        if (tid < 180) {
            int d = tid >> 2, p = tid & 3;
            int tt = c_PT[d], ss = c_PS[d];
            const uint16_t* ap = sT1 + tt * LDK + (p << 3);
            const uint16_t* bp = A2 + ss * LDK + (p << 3);
            float da = 0.f;
#pragma unroll
            for (int c = 0; c < 256; c += 32) {
                uint4 ua = *(const uint4*)(ap + c);
                uint4 ub = *(const uint4*)(bp + c);
                da = fmaf(bflo(ua.x), bflo(ub.x), da);
                da = fmaf(bfhi(ua.x), bfhi(ub.x), da);
                da = fmaf(bflo(ua.y), bflo(ub.y), da);
                da = fmaf(bfhi(ua.y), bfhi(ub.y), da);
                da = fmaf(bflo(ua.z), bflo(ub.z), da);
                da = fmaf(bfhi(ua.z), bfhi(ub.z), da);
                da = fmaf(bflo(ua.w), bflo(ub.w), da);
                da = fmaf(bfhi(ua.w), bfhi(ub.w), da);
            }
            da += __shfl_xor(da, 1);
            da += __shfl_xor(da, 2);
            if (p == 0) s_sim[d] = da;
        }

#pragma unroll
        for (int p = 0; p < 2; ++p)
#pragma unroll
            for (int q = 0; q < 4; ++q)
                acc[p][q] = f32x4{0.f, 0.f, 0.f, 0.f};
#pragma unroll
        for (int kk = 0; kk < 8; ++kk) {
            const int ko = kk * 32 + ((lane >> 4) << 3);
            bf16x8 y0 = __builtin_bit_cast(bf16x8, *(const uint4*)(A2 + r0 * LDK + ko));
            bf16x8 y1 = __builtin_bit_cast(bf16x8, *(const uint4*)(A2 + r1 * LDK + ko));
            bf16x8 bf[4];
#pragma unroll
            for (int ct = 0; ct < 4; ++ct)
                bf[ct] = __builtin_bit_cast(bf16x8,
                    *(const uint4*)(bv + (((kk << 2) + ct) * 64 + lane) * 8));
#pragma unroll
            for (int ct = 0; ct < 4; ++ct) {
                acc[0][ct] = __builtin_amdgcn_mfma_f32_16x16x32_bf16(y0, bf[ct], acc[0][ct], 0, 0, 0);
                acc[1][ct] = __builtin_amdgcn_mfma_f32_16x16x32_bf16(y1, bf[ct], acc[1][ct], 0, 0, 0);
            }
        }
        storeD(sV, w << 6, lane, acc);
        LGKM_BAR();   // B2: v + s_sim visible

        // ---- phase C: combine with inline softmax; then write next stage ----
        const size_t ob = blockBase + (size_t)i * TT * CC;
#pragma unroll
        for (int pass = 0; pass < 3; ++pass) {
            int u = tid + (pass << 8);
            if (u < 640) {
                int r  = u >> 5;
                int ch = (u & 31) << 3;
                float o[8] = {0.f, 0.f, 0.f, 0.f, 0.f, 0.f, 0.f, 0.f};
                if (r == 16) {
                    const uint16_t* vb = &sV[ch];
#pragma unroll
                    for (int ss = 0; ss < TT; ++ss)
                        acc8(o, *(const uint4*)(vb + ss * LDK), 0.05f);
                } else {
                    int cnt = c_CNT[r];
                    int off = c_OFF[r];
                    float m = -1e30f;
#pragma unroll
                    for (int j = 0; j < 4; ++j)
                        if (j < cnt) m = fmaxf(m, s_sim[off + j]);
                    float e[4] = {0.f, 0.f, 0.f, 0.f};
                    float sum = 0.f;
#pragma unroll
                    for (int j = 0; j < 4; ++j)
                        if (j < cnt) { e[j] = __expf(s_sim[off + j] - m); sum += e[j]; }
                    float inv = 1.f / sum;
#pragma unroll
                    for (int j = 0; j < 4; ++j)
                        if (j < cnt)
                            acc8(o, *(const uint4*)&sV[c_COLS[r][j] * LDK + ch], e[j] * inv);
                }
                float* op = outg + ob + (size_t)r * CC + ch;
                *(float4*)op       = make_float4(o[0], o[1], o[2], o[3]);
                *(float4*)(op + 4) = make_float4(o[4], o[5], o[6], o[7]);
            }
        }
        if (hasNext) {   // consume prefetch (compiler inserts exact vmcnt wait here)
#pragma unroll
            for (int j = 0; j < 5; ++j) {
                int s  = tid + (j << 8);
                int r  = s >> 6;
                int c4 = (s & 63) << 2;
                uint2 ua; ua.x = pk2(p1[j].x, p1[j].y); ua.y = pk2(p1[j].z, p1[j].w);
                uint2 ub; ub.x = pk2(p2[j].x, p2[j].y); ub.y = pk2(p2[j].z, p2[j].w);
                *(uint2*)&sF1[nxt][r * LDK + c4] = ua;
                *(uint2*)&sF2[nxt][r * LDK + c4] = ub;
            }
        }
        LGKM_BAR();   // B3: next stage visible; sT1/sV/s_sim free
    }
}

extern "C" void kernel_launch(void* const* d_in, const int* in_sizes, int n_in,
                              void* d_out, int out_size, void* d_ws, size_t ws_size,
                              hipStream_t stream) {
    const float* feat1 = (const float*)d_in[0];
    const float* feat2 = (const float*)d_in[1];
    const float* Wq    = (const float*)d_in[2];
    const float* Wk    = (const float*)d_in[3];
    const float* Wv    = (const float*)d_in[4];
    uint16_t* mqkT = (uint16_t*)d_ws;          // 128 KB
    uint16_t* wvb  = mqkT + CC * CC;           // 128 KB
    uint16_t* BqS  = wvb  + CC * CC;           // 128 KB (swizzled)
    uint16_t* BvS  = BqS  + CC * CC;           // 128 KB (swizzled)

    prep1_kernel<<<CC, CC, 0, stream>>>(Wq, Wk, Wv, mqkT, wvb);
    prep2_kernel<<<64, NT, 0, stream>>>(mqkT, wvb, BqS, BvS);
    attn_main<<<NBATCH / BPB, NT, 0, stream>>>(feat1, feat2, BqS, BvS, (float*)d_out);
}

// Round 7
// 399.164 us; speedup vs baseline: 2.7526x; 2.7526x over previous
//
#include <hip/hip_runtime.h>
#include <stdint.h>

#define NBATCH 16384
#define TT     20
#define CC     256
#define LDK    264   // LDS row stride (bf16 elems)
#define NB     2
#define NROW   40    // NB*TT
#define NT     256   // 4 waves

typedef __bf16 bf16x8 __attribute__((ext_vector_type(8)));
typedef float  f32x4  __attribute__((ext_vector_type(4)));

// Active-column tables from tb_mask(T=20, win=3):
// t=0,1:{0,1,2}  t=2:{0,1,2,3}  t=3..15:{t,t+1}  t=16: uniform 1/20  t=17..19:{17,18,19}
__constant__ int8_t c_CNT[TT]     = {3,3,4,2,2,2,2,2,2,2,2,2,2,2,2,2,0,3,3,3};
__constant__ int8_t c_OFF[TT]     = {0,3,6,10,12,14,16,18,20,22,24,26,28,30,32,34,0,36,39,42};
__constant__ int8_t c_COLS[TT][4] = {
    {0,1,2,0},{0,1,2,0},{0,1,2,3},
    {3,4,0,0},{4,5,0,0},{5,6,0,0},{6,7,0,0},{7,8,0,0},{8,9,0,0},
    {9,10,0,0},{10,11,0,0},{11,12,0,0},{12,13,0,0},{13,14,0,0},
    {14,15,0,0},{15,16,0,0},{0,0,0,0},
    {17,18,19,0},{17,18,19,0},{17,18,19,0}};
__constant__ int8_t c_PT[45] = {0,0,0,1,1,1,2,2,2,2,3,3,4,4,5,5,6,6,7,7,8,8,9,9,
                                10,10,11,11,12,12,13,13,14,14,15,15,17,17,17,18,18,18,19,19,19};
__constant__ int8_t c_PS[45] = {0,1,2,0,1,2,0,1,2,3,3,4,4,5,5,6,6,7,7,8,8,9,9,10,
                                10,11,11,12,12,13,13,14,14,15,15,16,17,18,19,17,18,19,17,18,19};

__device__ __forceinline__ uint16_t f2bf(float f) {
    __bf16 b = (__bf16)f;
    return __builtin_bit_cast(uint16_t, b);
}
__device__ __forceinline__ uint32_t pk2(float a, float b) {
    return (uint32_t)f2bf(a) | ((uint32_t)f2bf(b) << 16);
}
__device__ __forceinline__ float bflo(uint32_t u) { return __builtin_bit_cast(float, u << 16); }
__device__ __forceinline__ float bfhi(uint32_t u) { return __builtin_bit_cast(float, u & 0xffff0000u); }

// prep1: mqkT[n][k] = sum_h Wk[h,n]*Wq[h,k] / 16 ;  wvb[n][k] = bf16(Wv[n][k])
__global__ void prep1_kernel(const float* __restrict__ Wq, const float* __restrict__ Wk,
                             const float* __restrict__ Wv, uint16_t* __restrict__ mqkT,
                             uint16_t* __restrict__ wvb) {
    const int n = blockIdx.x;
    const int k = threadIdx.x;
    float acc = 0.f;
    for (int h = 0; h < CC; ++h)
        acc = fmaf(Wk[h * CC + n], Wq[h * CC + k], acc);
    mqkT[n * CC + k] = f2bf(acc * 0.0625f);
    wvb[n * CC + k]  = f2bf(Wv[n * CC + k]);
}

// prep2: swizzle B^T tables into per-wave MFMA fragment order (one coalesced 1KB load per frag)
__global__ void prep2_kernel(const uint16_t* __restrict__ mqkT, const uint16_t* __restrict__ wvb,
                             uint16_t* __restrict__ BqS, uint16_t* __restrict__ BvS) {
    const int bid = blockIdx.x;          // 0..63 : m*32 + w*8 + kk
    const int m  = bid >> 5;
    const int w  = (bid >> 3) & 3;
    const int kk = bid & 7;
    const int ct   = threadIdx.x >> 6;
    const int lane = threadIdx.x & 63;
    const uint16_t* src = m ? wvb : mqkT;
    uint16_t*       dst = m ? BvS : BqS;
    const int n   = w * 64 + ct * 16 + (lane & 15);
    const int col = kk * 32 + ((lane >> 4) << 3);
    uint4 v = *(const uint4*)(src + n * CC + col);
    *(uint4*)(dst + ((size_t)((w * 32 + kk * 4 + ct) * 64 + lane) << 3)) = v;
}

// D layout (m89): col = lane&15, row = 4*(lane>>4)+j.  64-col wave panel at wcol.
// 3 row-tiles cover rows 0..47; rows >= NROW discarded (they carry garbage-in garbage-out).
__device__ __forceinline__ void storeD(uint16_t* __restrict__ sD, int wcol, int lane,
                                       f32x4 acc[3][4]) {
    const int drow = (lane >> 4) << 2;
    const int dcol = lane & 15;
#pragma unroll
    for (int rt = 0; rt < 3; ++rt)
#pragma unroll
        for (int ct = 0; ct < 4; ++ct)
#pragma unroll
            for (int j = 0; j < 4; ++j) {
                int row = rt * 16 + drow + j;
                if (row < NROW)
                    sD[row * LDK + (wcol + ct * 16 + dcol)] = f2bf(acc[rt][ct][j]);
            }
}

__device__ __forceinline__ void acc8(float* o, uint4 uv, float wgt) {
    o[0] = fmaf(bflo(uv.x), wgt, o[0]);
    o[1] = fmaf(bfhi(uv.x), wgt, o[1]);
    o[2] = fmaf(bflo(uv.y), wgt, o[2]);
    o[3] = fmaf(bfhi(uv.y), wgt, o[3]);
    o[4] = fmaf(bflo(uv.z), wgt, o[4]);
    o[5] = fmaf(bfhi(uv.z), wgt, o[5]);
    o[6] = fmaf(bflo(uv.w), wgt, o[6]);
    o[7] = fmaf(bfhi(uv.w), wgt, o[7]);
}

__global__ __launch_bounds__(NT, 4)
void attn_main(const float* __restrict__ f1g, const float* __restrict__ f2g,
               const uint16_t* __restrict__ BqS, const uint16_t* __restrict__ BvS,
               float* __restrict__ outg) {
    __shared__ uint16_t sF1[48 * LDK];   // feat1 (rows 0..39) -> later v; rows 40..47 never written
    __shared__ uint16_t sF2[48 * LDK];   // feat2
    __shared__ uint16_t sT [NROW * LDK]; // t1
    __shared__ float    s_sim[NB * 45];

    const int tid  = threadIdx.x;
    const int lane = tid & 63;
    const int w    = tid >> 6;            // wave owns 64 output cols
    const int lrow = lane & 15;
    const int lk8  = (lane >> 4) << 3;
    const size_t base = (size_t)blockIdx.x * NROW * CC;
    const float* f1 = f1g + base;
    const float* f2 = f2g + base;

    // ---- stage: issue ALL 20 global loads first (one latency exposure), then convert+write ----
    float4 va[10], vb[10];
#pragma unroll
    for (int j = 0; j < 10; ++j) {
        int s = tid + (j << 8);           // 0..2559 float4 slots (40 rows x 64 per tensor)
        va[j] = *(const float4*)(f1 + (s << 2));
        vb[j] = *(const float4*)(f2 + (s << 2));
    }
#pragma unroll
    for (int j = 0; j < 10; ++j) {
        int s  = tid + (j << 8);
        int r  = s >> 6;                  // 0..39
        int c4 = (s & 63) << 2;           // 0..252
        uint2 ua; ua.x = pk2(va[j].x, va[j].y); ua.y = pk2(va[j].z, va[j].w);
        uint2 ub; ub.x = pk2(vb[j].x, vb[j].y); ub.y = pk2(vb[j].z, vb[j].w);
        *(uint2*)&sF1[r * LDK + c4] = ua;
        *(uint2*)&sF2[r * LDK + c4] = ub;
    }
    __syncthreads();                      // B1

    const uint16_t* bq = BqS + ((size_t)w << 14);
    const uint16_t* bv = BvS + ((size_t)w << 14);

    // ---- GEMM1: t1 = feat1 * Mqk (48 rows x 64 cols per wave) ----
    f32x4 acc[3][4];
#pragma unroll
    for (int p = 0; p < 3; ++p)
#pragma unroll
        for (int q = 0; q < 4; ++q)
            acc[p][q] = f32x4{0.f, 0.f, 0.f, 0.f};
#pragma unroll
    for (int kk = 0; kk < 8; ++kk) {
        const int ko = kk * 32 + lk8;
        bf16x8 a0 = __builtin_bit_cast(bf16x8, *(const uint4*)(sF1 + lrow * LDK + ko));
        bf16x8 a1 = __builtin_bit_cast(bf16x8, *(const uint4*)(sF1 + (16 + lrow) * LDK + ko));
        bf16x8 a2 = __builtin_bit_cast(bf16x8, *(const uint4*)(sF1 + (32 + lrow) * LDK + ko));
        bf16x8 bf[4];
#pragma unroll
        for (int ct = 0; ct < 4; ++ct)
            bf[ct] = __builtin_bit_cast(bf16x8,
                *(const uint4*)(bq + (((kk << 2) + ct) * 64 + lane) * 8));
#pragma unroll
        for (int ct = 0; ct < 4; ++ct) {
            acc[0][ct] = __builtin_amdgcn_mfma_f32_16x16x32_bf16(a0, bf[ct], acc[0][ct], 0, 0, 0);
            acc[1][ct] = __builtin_amdgcn_mfma_f32_16x16x32_bf16(a1, bf[ct], acc[1][ct], 0, 0, 0);
            acc[2][ct] = __builtin_amdgcn_mfma_f32_16x16x32_bf16(a2, bf[ct], acc[2][ct], 0, 0, 0);
        }
    }
    storeD(sT, w << 6, lane, acc);        // sT untouched until B2 -> no pre-store barrier needed
    __syncthreads();                      // B2: t1 visible; all sF1 GEMM reads done

    // ---- sim (90 dots x 2 threads x 128 ch) + GEMM2: v = feat2 * Wv^T ----
    if (tid < 180) {
        int d  = tid >> 1;
        int p  = tid & 1;
        int lb = (d >= 45) ? 1 : 0;
        int pd = d - lb * 45;
        int t = c_PT[pd], s = c_PS[pd];
        const uint16_t* ap = &sT [(lb * TT + t) * LDK + (p << 7)];
        const uint16_t* bp = &sF2[(lb * TT + s) * LDK + (p << 7)];
        float da = 0.f;
#pragma unroll
        for (int c = 0; c < 128; c += 8) {
            uint4 ua = *(const uint4*)(ap + c);
            uint4 ub = *(const uint4*)(bp + c);
            da = fmaf(bflo(ua.x), bflo(ub.x), da);
            da = fmaf(bfhi(ua.x), bfhi(ub.x), da);
            da = fmaf(bflo(ua.y), bflo(ub.y), da);
            da = fmaf(bfhi(ua.y), bfhi(ub.y), da);
            da = fmaf(bflo(ua.z), bflo(ub.z), da);
            da = fmaf(bfhi(ua.z), bfhi(ub.z), da);
            da = fmaf(bflo(ua.w), bflo(ub.w), da);
            da = fmaf(bfhi(ua.w), bfhi(ub.w), da);
        }
        da += __shfl_xor(da, 1);
        if (p == 0) s_sim[d] = da;
    }

#pragma unroll
    for (int p = 0; p < 3; ++p)
#pragma unroll
        for (int q = 0; q < 4; ++q)
            acc[p][q] = f32x4{0.f, 0.f, 0.f, 0.f};
#pragma unroll
    for (int kk = 0; kk < 8; ++kk) {
        const int ko = kk * 32 + lk8;
        bf16x8 a0 = __builtin_bit_cast(bf16x8, *(const uint4*)(sF2 + lrow * LDK + ko));
        bf16x8 a1 = __builtin_bit_cast(bf16x8, *(const uint4*)(sF2 + (16 + lrow) * LDK + ko));
        bf16x8 a2 = __builtin_bit_cast(bf16x8, *(const uint4*)(sF2 + (32 + lrow) * LDK + ko));
        bf16x8 bf[4];
#pragma unroll
        for (int ct = 0; ct < 4; ++ct)
            bf[ct] = __builtin_bit_cast(bf16x8,
                *(const uint4*)(bv + (((kk << 2) + ct) * 64 + lane) * 8));
#pragma unroll
        for (int ct = 0; ct < 4; ++ct) {
            acc[0][ct] = __builtin_amdgcn_mfma_f32_16x16x32_bf16(a0, bf[ct], acc[0][ct], 0, 0, 0);
            acc[1][ct] = __builtin_amdgcn_mfma_f32_16x16x32_bf16(a1, bf[ct], acc[1][ct], 0, 0, 0);
            acc[2][ct] = __builtin_amdgcn_mfma_f32_16x16x32_bf16(a2, bf[ct], acc[2][ct], 0, 0, 0);
        }
    }
    storeD(sF1, w << 6, lane, acc);       // v over feat1 (sF1 readers done at B2)
    __syncthreads();                      // B3: v + s_sim visible

    // ---- combine with inline softmax; coalesced out (1280 units of 8 ch) ----
#pragma unroll
    for (int pass = 0; pass < 5; ++pass) {
        int u  = tid + (pass << 8);       // 0..1279
        int r  = u >> 5;                  // 0..39
        int ch = (u & 31) << 3;           // 0..248
        int lb = (r >= TT) ? 1 : 0;
        int t  = r - lb * TT;
        const uint16_t* vrows = &sF1[lb * TT * LDK];
        float o[8] = {0.f, 0.f, 0.f, 0.f, 0.f, 0.f, 0.f, 0.f};
        if (t == 16) {
#pragma unroll
            for (int ss = 0; ss < TT; ++ss)
                acc8(o, *(const uint4*)(vrows + ss * LDK + ch), 0.05f);
        } else {
            int cnt = c_CNT[t];
            int off = lb * 45 + c_OFF[t];
            float m = -1e30f;
#pragma unroll
            for (int j = 0; j < 4; ++j)
                if (j < cnt) m = fmaxf(m, s_sim[off + j]);
            float e[4] = {0.f, 0.f, 0.f, 0.f};
            float sum = 0.f;
#pragma unroll
            for (int j = 0; j < 4; ++j)
                if (j < cnt) { e[j] = __expf(s_sim[off + j] - m); sum += e[j]; }
            float inv = 1.f / sum;
#pragma unroll
            for (int j = 0; j < 4; ++j)
                if (j < cnt)
                    acc8(o, *(const uint4*)(vrows + c_COLS[t][j] * LDK + ch), e[j] * inv);
        }
        float* op = outg + base + (size_t)r * CC + ch;
        *(float4*)op       = make_float4(o[0], o[1], o[2], o[3]);
        *(float4*)(op + 4) = make_float4(o[4], o[5], o[6], o[7]);
    }
}

extern "C" void kernel_launch(void* const* d_in, const int* in_sizes, int n_in,
                              void* d_out, int out_size, void* d_ws, size_t ws_size,
                              hipStream_t stream) {
    const float* feat1 = (const float*)d_in[0];
    const float* feat2 = (const float*)d_in[1];
    const float* Wq    = (const float*)d_in[2];
    const float* Wk    = (const float*)d_in[3];
    const float* Wv    = (const float*)d_in[4];
    uint16_t* mqkT = (uint16_t*)d_ws;          // 128 KB
    uint16_t* wvb  = mqkT + CC * CC;           // 128 KB
    uint16_t* BqS  = wvb  + CC * CC;           // 128 KB (swizzled)
    uint16_t* BvS  = BqS  + CC * CC;           // 128 KB (swizzled)

    prep1_kernel<<<CC, CC, 0, stream>>>(Wq, Wk, Wv, mqkT, wvb);
    prep2_kernel<<<64, NT, 0, stream>>>(mqkT, wvb, BqS, BvS);
    attn_main<<<NBATCH / NB, NT, 0, stream>>>(feat1, feat2, BqS, BvS, (float*)d_out);
}

// Round 8
// 372.473 us; speedup vs baseline: 2.9498x; 1.0717x over previous
//
#include <hip/hip_runtime.h>
#include <stdint.h>

#define NBATCH 16384
#define TT     20
#define CC     256
#define LDK    264   // LDS row stride for bf16 buffers (sT / sV)
#define NT     256   // 4 waves

typedef __bf16 bf16x8 __attribute__((ext_vector_type(8)));
typedef float  f32x4  __attribute__((ext_vector_type(4)));

// async fp32 stage: per-lane global src, wave-uniform LDS row base (lane*16B auto-offset)
#define GLL16(g, l) __builtin_amdgcn_global_load_lds( \
    (const __attribute__((address_space(1))) uint32_t*)(g), \
    (__attribute__((address_space(3))) uint32_t*)(l), 16, 0, 0)

// Active-column tables from tb_mask(T=20, win=3):
// t=0,1:{0,1,2}  t=2:{0,1,2,3}  t=3..15:{t,t+1}  t=16: uniform 1/20  t=17..19:{17,18,19}
__constant__ int8_t c_CNT[TT]     = {3,3,4,2,2,2,2,2,2,2,2,2,2,2,2,2,0,3,3,3};
__constant__ int8_t c_OFF[TT]     = {0,3,6,10,12,14,16,18,20,22,24,26,28,30,32,34,0,36,39,42};
__constant__ int8_t c_COLS[TT][4] = {
    {0,1,2,0},{0,1,2,0},{0,1,2,3},
    {3,4,0,0},{4,5,0,0},{5,6,0,0},{6,7,0,0},{7,8,0,0},{8,9,0,0},
    {9,10,0,0},{10,11,0,0},{11,12,0,0},{12,13,0,0},{13,14,0,0},
    {14,15,0,0},{15,16,0,0},{0,0,0,0},
    {17,18,19,0},{17,18,19,0},{17,18,19,0}};
__constant__ int8_t c_PT[45] = {0,0,0,1,1,1,2,2,2,2,3,3,4,4,5,5,6,6,7,7,8,8,9,9,
                                10,10,11,11,12,12,13,13,14,14,15,15,17,17,17,18,18,18,19,19,19};
__constant__ int8_t c_PS[45] = {0,1,2,0,1,2,0,1,2,3,3,4,4,5,5,6,6,7,7,8,8,9,9,10,
                                10,11,11,12,12,13,13,14,14,15,15,16,17,18,19,17,18,19,17,18,19};

__device__ __forceinline__ uint16_t f2bf(float f) {
    __bf16 b = (__bf16)f;
    return __builtin_bit_cast(uint16_t, b);
}
__device__ __forceinline__ uint32_t pk2(float a, float b) {
    return (uint32_t)f2bf(a) | ((uint32_t)f2bf(b) << 16);
}
__device__ __forceinline__ float bflo(uint32_t u) { return __builtin_bit_cast(float, u << 16); }
__device__ __forceinline__ float bfhi(uint32_t u) { return __builtin_bit_cast(float, u & 0xffff0000u); }

// prep1: mqkT[n][k] = sum_h Wk[h,n]*Wq[h,k] / 16 ;  wvb[n][k] = bf16(Wv[n][k])
__global__ void prep1_kernel(const float* __restrict__ Wq, const float* __restrict__ Wk,
                             const float* __restrict__ Wv, uint16_t* __restrict__ mqkT,
                             uint16_t* __restrict__ wvb) {
    const int n = blockIdx.x;
    const int k = threadIdx.x;
    float acc = 0.f;
    for (int h = 0; h < CC; ++h)
        acc = fmaf(Wk[h * CC + n], Wq[h * CC + k], acc);
    mqkT[n * CC + k] = f2bf(acc * 0.0625f);
    wvb[n * CC + k]  = f2bf(Wv[n * CC + k]);
}

// prep2: swizzle B^T tables into per-wave MFMA fragment order (one coalesced 1KB load per frag)
__global__ void prep2_kernel(const uint16_t* __restrict__ mqkT, const uint16_t* __restrict__ wvb,
                             uint16_t* __restrict__ BqS, uint16_t* __restrict__ BvS) {
    const int bid = blockIdx.x;          // 0..63 : m*32 + w*8 + kk
    const int m  = bid >> 5;
    const int w  = (bid >> 3) & 3;
    const int kk = bid & 7;
    const int ct   = threadIdx.x >> 6;
    const int lane = threadIdx.x & 63;
    const uint16_t* src = m ? wvb : mqkT;
    uint16_t*       dst = m ? BvS : BqS;
    const int n   = w * 64 + ct * 16 + (lane & 15);
    const int col = kk * 32 + ((lane >> 4) << 3);
    uint4 v = *(const uint4*)(src + n * CC + col);
    *(uint4*)(dst + ((size_t)((w * 32 + kk * 4 + ct) * 64 + lane) << 3)) = v;
}

// A-frag from swizzled f32 LDS: 8 f32 of row r at 32B-unit u (u = k/8), convert to bf16x8.
__device__ __forceinline__ bf16x8 ldsA(const float* __restrict__ sF, int r, int u) {
    const float* p = sF + r * 256 + ((u ^ (r & 7)) << 3);
    float4 lo = *(const float4*)p;
    float4 hi = *(const float4*)(p + 4);
    uint4 q;
    q.x = pk2(lo.x, lo.y); q.y = pk2(lo.z, lo.w);
    q.z = pk2(hi.x, hi.y); q.w = pk2(hi.z, hi.w);
    return __builtin_bit_cast(bf16x8, q);
}

// D layout (m89): col = lane&15, row = 4*(lane>>4)+j.  64-col wave panel at wcol.
__device__ __forceinline__ void storeD(uint16_t* __restrict__ sD, int wcol, int lane,
                                       f32x4 acc[2][4]) {
    const int drow = (lane >> 4) << 2;
    const int dcol = lane & 15;
#pragma unroll
    for (int rt = 0; rt < 2; ++rt)
#pragma unroll
        for (int ct = 0; ct < 4; ++ct)
#pragma unroll
            for (int j = 0; j < 4; ++j) {
                int row = rt * 16 + drow + j;
                if (row < TT)
                    sD[row * LDK + (wcol + ct * 16 + dcol)] = f2bf(acc[rt][ct][j]);
            }
}

__device__ __forceinline__ void acc8(float* o, uint4 uv, float wgt) {
    o[0] = fmaf(bflo(uv.x), wgt, o[0]);
    o[1] = fmaf(bfhi(uv.x), wgt, o[1]);
    o[2] = fmaf(bflo(uv.y), wgt, o[2]);
    o[3] = fmaf(bfhi(uv.y), wgt, o[3]);
    o[4] = fmaf(bflo(uv.z), wgt, o[4]);
    o[5] = fmaf(bfhi(uv.z), wgt, o[5]);
    o[6] = fmaf(bflo(uv.w), wgt, o[6]);
    o[7] = fmaf(bfhi(uv.w), wgt, o[7]);
}

__global__ __launch_bounds__(NT, 3)
void attn_main(const float* __restrict__ f1g, const float* __restrict__ f2g,
               const uint16_t* __restrict__ BqS, const uint16_t* __restrict__ BvS,
               float* __restrict__ outg) {
    __shared__ float    sF1[TT * 256];   // feat1 f32 (swizzled rows); later overlaid by v (bf16)
    __shared__ float    sF2[TT * 256];   // feat2 f32 (swizzled rows)
    __shared__ uint16_t sT [TT * LDK];   // t1 bf16 (padded rows)
    __shared__ float    s_sim[45];
    uint16_t* sV = (uint16_t*)sF1;       // v overlays feat1 after GEMM1 reads complete

    const int tid  = threadIdx.x;
    const int lane = tid & 63;
    const int w    = tid >> 6;            // wave owns 64 output cols
    const int lrow = lane & 15;
    const size_t base = (size_t)blockIdx.x * TT * CC;
    const float* f1 = f1g + base;
    const float* f2 = f2g + base;

    // ---- stage: async DMA fp32 rows -> LDS; zero VGPRs, zero VALU ----
    // lane's global 16B chunk g is the inverse of the read-side XOR swizzle (unit ^= r&7)
    {
#pragma unroll
        for (int j = 0; j < 5; ++j) {
            int r = w * 5 + j;
            int g = ((((lane >> 1) ^ (r & 7)) << 1) | (lane & 1));
            GLL16(f1 + r * 256 + g * 4, &sF1[r * 256]);
            GLL16(f2 + r * 256 + g * 4, &sF2[r * 256]);
        }
    }
    __syncthreads();                      // B1 (drains the DMA)

    const uint16_t* bq = BqS + ((size_t)w << 14);
    const uint16_t* bv = BvS + ((size_t)w << 14);
    const int r0 = lrow;
    const int r1 = (16 + lrow < TT) ? (16 + lrow) : (TT - 1);
    const int usub = lane >> 4;           // which 8-f32 unit within the 32-f32 k-slice

    // ---- GEMM1: t1 = feat1 * Mqk (A cvt'd from f32 LDS, B streamed coalesced from L2) ----
    f32x4 acc[2][4];
#pragma unroll
    for (int p = 0; p < 2; ++p)
#pragma unroll
        for (int q = 0; q < 4; ++q)
            acc[p][q] = f32x4{0.f, 0.f, 0.f, 0.f};
#pragma unroll
    for (int kk = 0; kk < 8; ++kk) {
        const int u = (kk << 2) + usub;
        bf16x8 a0 = ldsA(sF1, r0, u);
        bf16x8 a1 = ldsA(sF1, r1, u);
        bf16x8 bf[4];
#pragma unroll
        for (int ct = 0; ct < 4; ++ct)
            bf[ct] = __builtin_bit_cast(bf16x8,
                *(const uint4*)(bq + (((kk << 2) + ct) * 64 + lane) * 8));
#pragma unroll
        for (int ct = 0; ct < 4; ++ct) {
            acc[0][ct] = __builtin_amdgcn_mfma_f32_16x16x32_bf16(a0, bf[ct], acc[0][ct], 0, 0, 0);
            acc[1][ct] = __builtin_amdgcn_mfma_f32_16x16x32_bf16(a1, bf[ct], acc[1][ct], 0, 0, 0);
        }
    }
    storeD(sT, w << 6, lane, acc);
    __syncthreads();                      // B2: t1 visible; all sF1 f32 reads done

    // ---- sim (45 dots x 4 thr): t1 (bf16) . feat2 (f32, swizzled) ----
    if (tid < 180) {
        int d = tid >> 2, p = tid & 3;
        int t = c_PT[d], s = c_PS[d];
        const uint16_t* ap = sT + t * LDK + (p << 6);
        float da = 0.f;
#pragma unroll
        for (int j = 0; j < 8; ++j) {
            int u = (p << 3) + j;
            const float* bp = sF2 + s * 256 + ((u ^ (s & 7)) << 3);
            float4 lo = *(const float4*)bp;
            float4 hi = *(const float4*)(bp + 4);
            uint4 ua = *(const uint4*)(ap + (j << 3));
            da = fmaf(bflo(ua.x), lo.x, da);
            da = fmaf(bfhi(ua.x), lo.y, da);
            da = fmaf(bflo(ua.y), lo.z, da);
            da = fmaf(bfhi(ua.y), lo.w, da);
            da = fmaf(bflo(ua.z), hi.x, da);
            da = fmaf(bfhi(ua.z), hi.y, da);
            da = fmaf(bflo(ua.w), hi.z, da);
            da = fmaf(bfhi(ua.w), hi.w, da);
        }
        da += __shfl_xor(da, 1);
        da += __shfl_xor(da, 2);
        if (p == 0) s_sim[d] = da;
    }

    // ---- GEMM2: v = feat2 * Wv^T (runs alongside sim threads' work) ----
#pragma unroll
    for (int p = 0; p < 2; ++p)
#pragma unroll
        for (int q = 0; q < 4; ++q)
            acc[p][q] = f32x4{0.f, 0.f, 0.f, 0.f};
#pragma unroll
    for (int kk = 0; kk < 8; ++kk) {
        const int u = (kk << 2) + usub;
        bf16x8 a0 = ldsA(sF2, r0, u);
        bf16x8 a1 = ldsA(sF2, r1, u);
        bf16x8 bf[4];
#pragma unroll
        for (int ct = 0; ct < 4; ++ct)
            bf[ct] = __builtin_bit_cast(bf16x8,
                *(const uint4*)(bv + (((kk << 2) + ct) * 64 + lane) * 8));
#pragma unroll
        for (int ct = 0; ct < 4; ++ct) {
            acc[0][ct] = __builtin_amdgcn_mfma_f32_16x16x32_bf16(a0, bf[ct], acc[0][ct], 0, 0, 0);
            acc[1][ct] = __builtin_amdgcn_mfma_f32_16x16x32_bf16(a1, bf[ct], acc[1][ct], 0, 0, 0);
        }
    }
    storeD(sV, w << 6, lane, acc);        // overlay onto sF1 (readers done at B2)
    __syncthreads();                      // B3: v + s_sim visible

    // ---- combine with inline softmax; coalesced f32 out ----
#pragma unroll
    for (int pass = 0; pass < 3; ++pass) {
        int u = tid + (pass << 8);        // 0..767, active < 640
        if (u < 640) {
            int r  = u >> 5;              // 0..19
            int ch = (u & 31) << 3;       // 0..248
            float o[8] = {0.f, 0.f, 0.f, 0.f, 0.f, 0.f, 0.f, 0.f};
            if (r == 16) {
#pragma unroll
                for (int ss = 0; ss < TT; ++ss)
                    acc8(o, *(const uint4*)(sV + ss * LDK + ch), 0.05f);
            } else {
                int cnt = c_CNT[r];
                int off = c_OFF[r];
                float m = -1e30f;
#pragma unroll
                for (int j = 0; j < 4; ++j)
                    if (j < cnt) m = fmaxf(m, s_sim[off + j]);
                float e[4] = {0.f, 0.f, 0.f, 0.f};
                float sum = 0.f;
#pragma unroll
                for (int j = 0; j < 4; ++j)
                    if (j < cnt) { e[j] = __expf(s_sim[off + j] - m); sum += e[j]; }
                float inv = 1.f / sum;
#pragma unroll
                for (int j = 0; j < 4; ++j)
                    if (j < cnt)
                        acc8(o, *(const uint4*)(sV + c_COLS[r][j] * LDK + ch), e[j] * inv);
            }
            float* op = outg + base + (size_t)r * CC + ch;
            *(float4*)op       = make_float4(o[0], o[1], o[2], o[3]);
            *(float4*)(op + 4) = make_float4(o[4], o[5], o[6], o[7]);
        }
    }
}

extern "C" void kernel_launch(void* const* d_in, const int* in_sizes, int n_in,
                              void* d_out, int out_size, void* d_ws, size_t ws_size,
                              hipStream_t stream) {
    const float* feat1 = (const float*)d_in[0];
    const float* feat2 = (const float*)d_in[1];
    const float* Wq    = (const float*)d_in[2];
    const float* Wk    = (const float*)d_in[3];
    const float* Wv    = (const float*)d_in[4];
    uint16_t* mqkT = (uint16_t*)d_ws;          // 128 KB
    uint16_t* wvb  = mqkT + CC * CC;           // 128 KB
    uint16_t* BqS  = wvb  + CC * CC;           // 128 KB (swizzled)
    uint16_t* BvS  = BqS  + CC * CC;           // 128 KB (swizzled)

    prep1_kernel<<<CC, CC, 0, stream>>>(Wq, Wk, Wv, mqkT, wvb);
    prep2_kernel<<<64, NT, 0, stream>>>(mqkT, wvb, BqS, BvS);
    attn_main<<<NBATCH, NT, 0, stream>>>(feat1, feat2, BqS, BvS, (float*)d_out);
}

// Round 9
// 347.567 us; speedup vs baseline: 3.1612x; 1.0717x over previous
//
#include <hip/hip_runtime.h>
#include <stdint.h>

#define NBATCH 16384
#define TT     20
#define CC     256
#define LDK    264   // sT row stride (u16): 528B, 16B-aligned
#define TP     40    // sVT inner stride (u16): 80B, 16B-aligned, good bank spread
#define NT     256   // 4 waves

typedef __bf16 bf16x8 __attribute__((ext_vector_type(8)));
typedef float  f32x4  __attribute__((ext_vector_type(4)));

// async fp32 stage: per-lane global src, wave-uniform LDS row base (lane*16B auto-offset)
#define GLL16(g, l) __builtin_amdgcn_global_load_lds( \
    (const __attribute__((address_space(1))) uint32_t*)(g), \
    (__attribute__((address_space(3))) uint32_t*)(l), 16, 0, 0)

// tb_mask tables: t=0,1:{0,1,2} t=2:{0,1,2,3} t=3..15:{t,t+1} t=16:uniform t=17..19:{17,18,19}
__constant__ int8_t c_CNT[TT] = {3,3,4,2,2,2,2,2,2,2,2,2,2,2,2,2,0,3,3,3};
__constant__ int8_t c_OFF[TT] = {0,3,6,10,12,14,16,18,20,22,24,26,28,30,32,34,0,36,39,42};
__constant__ int8_t c_PT[45]  = {0,0,0,1,1,1,2,2,2,2,3,3,4,4,5,5,6,6,7,7,8,8,9,9,
                                 10,10,11,11,12,12,13,13,14,14,15,15,17,17,17,18,18,18,19,19,19};
__constant__ int8_t c_PS[45]  = {0,1,2,0,1,2,0,1,2,3,3,4,4,5,5,6,6,7,7,8,8,9,9,10,
                                 10,11,11,12,12,13,13,14,14,15,15,16,17,18,19,17,18,19,17,18,19};

__device__ __forceinline__ uint16_t f2bf(float f) {
    __bf16 b = (__bf16)f;
    return __builtin_bit_cast(uint16_t, b);
}
__device__ __forceinline__ uint32_t pk2(float a, float b) {
    return (uint32_t)f2bf(a) | ((uint32_t)f2bf(b) << 16);
}
__device__ __forceinline__ float bflo(uint32_t u) { return __builtin_bit_cast(float, u << 16); }
__device__ __forceinline__ float bfhi(uint32_t u) { return __builtin_bit_cast(float, u & 0xffff0000u); }

// prep1: mqkT[n][k] = sum_h Wk[h,n]*Wq[h,k] / 16 ;  wvb[n][k] = bf16(Wv[n][k])
__global__ void prep1_kernel(const float* __restrict__ Wq, const float* __restrict__ Wk,
                             const float* __restrict__ Wv, uint16_t* __restrict__ mqkT,
                             uint16_t* __restrict__ wvb) {
    const int n = blockIdx.x;
    const int k = threadIdx.x;
    float acc = 0.f;
    for (int h = 0; h < CC; ++h)
        acc = fmaf(Wk[h * CC + n], Wq[h * CC + k], acc);
    mqkT[n * CC + k] = f2bf(acc * 0.0625f);
    wvb[n * CC + k]  = f2bf(Wv[n * CC + k]);
}

// prep2: swizzle tables into per-wave MFMA fragment order (one coalesced 1KB load per frag)
__global__ void prep2_kernel(const uint16_t* __restrict__ mqkT, const uint16_t* __restrict__ wvb,
                             uint16_t* __restrict__ BqS, uint16_t* __restrict__ BvS) {
    const int bid = blockIdx.x;          // 0..63 : m*32 + w*8 + kk
    const int m  = bid >> 5;
    const int w  = (bid >> 3) & 3;
    const int kk = bid & 7;
    const int ct   = threadIdx.x >> 6;
    const int lane = threadIdx.x & 63;
    const uint16_t* src = m ? wvb : mqkT;
    uint16_t*       dst = m ? BvS : BqS;
    const int n   = w * 64 + ct * 16 + (lane & 15);
    const int col = kk * 32 + ((lane >> 4) << 3);
    uint4 v = *(const uint4*)(src + n * CC + col);
    *(uint4*)(dst + ((size_t)((w * 32 + kk * 4 + ct) * 64 + lane) << 3)) = v;
}

// frag (8 f32 -> bf16x8) from swizzled f32 LDS row r, 8-f32 unit u
__device__ __forceinline__ bf16x8 ldsA(const float* __restrict__ sF, int r, int u) {
    const float* p = sF + r * 256 + ((u ^ (r & 7)) << 3);
    float4 lo = *(const float4*)p;
    float4 hi = *(const float4*)(p + 4);
    uint4 q;
    q.x = pk2(lo.x, lo.y); q.y = pk2(lo.z, lo.w);
    q.z = pk2(hi.x, hi.y); q.w = pk2(hi.z, hi.w);
    return __builtin_bit_cast(bf16x8, q);
}

__global__ __launch_bounds__(NT, 3)
void attn_main(const float* __restrict__ f1g, const float* __restrict__ f2g,
               const uint16_t* __restrict__ BqS, const uint16_t* __restrict__ BvS,
               float* __restrict__ outg) {
    __shared__ float    sF1[TT * 256];     // feat1 f32 (swizzled); overlaid by sVT after B2
    __shared__ float    sF2[TT * 256];     // feat2 f32 (swizzled)
    __shared__ uint16_t sT [TT * LDK];     // t1 bf16 row-major [t][h]
    __shared__ uint16_t attnL[32 * 32];    // exp-weights, padded, bf16
    __shared__ float    s_simE[45];        // exp(sim) per masked dot
    uint16_t* sVT = (uint16_t*)sF1;        // v^T bf16 [256][TP]

    const int tid  = threadIdx.x;
    const int lane = tid & 63;
    const int w    = tid >> 6;             // wave owns 64 hid cols
    const int l15  = lane & 15;
    const int q    = lane >> 4;
    const size_t base = (size_t)blockIdx.x * TT * CC;
    const float* f1 = f1g + base;
    const float* f2 = f2g + base;

    // ---- stage: async DMA fp32 rows -> LDS (inverse-swizzled global chunk per lane) ----
#pragma unroll
    for (int j = 0; j < 5; ++j) {
        int r = w * 5 + j;
        int g = (((lane >> 1) ^ (r & 7)) << 1) | (lane & 1);
        GLL16(f1 + r * 256 + g * 4, &sF1[r * 256]);
        GLL16(f2 + r * 256 + g * 4, &sF2[r * 256]);
    }
    // prefill attnL: zeros; row16 cols 0..19 = 1.0 (uniform-row trick)
    {
        uint32_t* aL = (uint32_t*)attnL;
#pragma unroll
        for (int rep = 0; rep < 2; ++rep) {
            int s = tid + (rep << 8);
            aL[s] = ((s >> 4) == 16 && (s & 15) < 10) ? 0x3F803F80u : 0u;
        }
    }
    __syncthreads();                       // B1

    const uint16_t* bq = BqS + ((size_t)w << 14);
    const uint16_t* bv = BvS + ((size_t)w << 14);
    const int rB0 = l15;
    const int rB1 = (16 + l15 < TT) ? 16 + l15 : TT - 1;

    // ---- phase A: GEMM1 swapped -> t1^T; D j-dim is hid-contiguous -> b64 stores ----
    {
        f32x4 acc[4][2];
#pragma unroll
        for (int mt = 0; mt < 4; ++mt)
#pragma unroll
            for (int ct = 0; ct < 2; ++ct)
                acc[mt][ct] = f32x4{0.f, 0.f, 0.f, 0.f};
#pragma unroll
        for (int kk = 0; kk < 8; ++kk) {
            const int u = (kk << 2) + q;
            bf16x8 b0 = ldsA(sF1, rB0, u);
            bf16x8 b1 = ldsA(sF1, rB1, u);
#pragma unroll
            for (int mt = 0; mt < 4; ++mt) {
                bf16x8 am = __builtin_bit_cast(bf16x8,
                    *(const uint4*)(bq + (((kk << 2) + mt) * 64 + lane) * 8));
                acc[mt][0] = __builtin_amdgcn_mfma_f32_16x16x32_bf16(am, b0, acc[mt][0], 0, 0, 0);
                acc[mt][1] = __builtin_amdgcn_mfma_f32_16x16x32_bf16(am, b1, acc[mt][1], 0, 0, 0);
            }
        }
        // D: lane holds t1^T[m = mt*16+4q+j][t = ct*16+l15] -> sT[t][h], j contiguous in h
#pragma unroll
        for (int mt = 0; mt < 4; ++mt)
#pragma unroll
            for (int ct = 0; ct < 2; ++ct) {
                int t = ct * 16 + l15;
                if (t < TT) {
                    int h0 = (w << 6) + mt * 16 + (q << 2);
                    uint2 u2;
                    u2.x = pk2(acc[mt][ct][0], acc[mt][ct][1]);
                    u2.y = pk2(acc[mt][ct][2], acc[mt][ct][3]);
                    *(uint2*)&sT[t * LDK + h0] = u2;
                }
            }
    }
    __syncthreads();                       // B2: sT visible; sF1 reads done

    // ---- phase B: GEMM2 (v) -> sVT transposed; sim+exp fused (no extra barrier) ----
    {
        f32x4 av[2][4];
#pragma unroll
        for (int rt = 0; rt < 2; ++rt)
#pragma unroll
            for (int ct = 0; ct < 4; ++ct)
                av[rt][ct] = f32x4{0.f, 0.f, 0.f, 0.f};
#pragma unroll
        for (int kk = 0; kk < 8; ++kk) {
            const int u = (kk << 2) + q;
            bf16x8 a0 = ldsA(sF2, rB0, u);
            bf16x8 a1 = ldsA(sF2, rB1, u);
#pragma unroll
            for (int ct = 0; ct < 4; ++ct) {
                bf16x8 bm = __builtin_bit_cast(bf16x8,
                    *(const uint4*)(bv + (((kk << 2) + ct) * 64 + lane) * 8));
                av[0][ct] = __builtin_amdgcn_mfma_f32_16x16x32_bf16(a0, bm, av[0][ct], 0, 0, 0);
                av[1][ct] = __builtin_amdgcn_mfma_f32_16x16x32_bf16(a1, bm, av[1][ct], 0, 0, 0);
            }
        }
        // D: lane holds v[t = rt*16+4q+j][h = w*64+ct*16+l15] -> sVT[h][t], j contiguous in t.
        // rt=1/q>0 lanes write zeros at t=20..31 (poison bytes could alias bf16-NaN).
#pragma unroll
        for (int ct = 0; ct < 4; ++ct) {
            int h = (w << 6) + ct * 16 + l15;
            {
                uint2 u2;
                u2.x = pk2(av[0][ct][0], av[0][ct][1]);
                u2.y = pk2(av[0][ct][2], av[0][ct][3]);
                *(uint2*)&sVT[h * TP + (q << 2)] = u2;
            }
            {
                uint2 u2;
                if (q == 0) {
                    u2.x = pk2(av[1][ct][0], av[1][ct][1]);
                    u2.y = pk2(av[1][ct][2], av[1][ct][3]);
                } else { u2.x = 0u; u2.y = 0u; }
                *(uint2*)&sVT[h * TP + 16 + (q << 2)] = u2;
            }
        }
    }
    // sim: 45 dots x 4 lanes x 64ch; exp (no max-sub: |sim| ~< 4) written straight to attnL
    if (tid < 180) {
        int d = tid >> 2, p = tid & 3;
        int t = c_PT[d], s = c_PS[d];
        const uint16_t* ap = sT + t * LDK + (p << 3);
        const float* f2r = sF2 + s * 256;
        const int sw = s & 7;
        float da = 0.f;
#pragma unroll
        for (int j = 0; j < 8; ++j) {
            uint4 ua = *(const uint4*)(ap + (j << 5));        // ch = p*8 + 32j
            const float* bp = f2r + (((p + (j << 2)) ^ sw) << 3);
            float4 lo = *(const float4*)bp;
            float4 hi = *(const float4*)(bp + 4);
            da = fmaf(bflo(ua.x), lo.x, da);
            da = fmaf(bfhi(ua.x), lo.y, da);
            da = fmaf(bflo(ua.y), lo.z, da);
            da = fmaf(bfhi(ua.y), lo.w, da);
            da = fmaf(bflo(ua.z), hi.x, da);
            da = fmaf(bfhi(ua.z), hi.y, da);
            da = fmaf(bflo(ua.w), hi.z, da);
            da = fmaf(bfhi(ua.w), hi.w, da);
        }
        da += __shfl_xor(da, 1);
        da += __shfl_xor(da, 2);
        if (p == 0) {
            float e = __expf(da);
            attnL[t * 32 + s] = f2bf(e);
            s_simE[d] = e;
        }
    }
    __syncthreads();                       // B3: attnL, s_simE, sVT visible

    // ---- phase C: PV via MFMA (K=32 one shot) + normalize-at-store ----
    {
        bf16x8 pa0 = __builtin_bit_cast(bf16x8, *(const uint4*)&attnL[l15 * 32 + (q << 3)]);
        bf16x8 pa1 = __builtin_bit_cast(bf16x8, *(const uint4*)&attnL[(16 + l15) * 32 + (q << 3)]);
        const f32x4 z = f32x4{0.f, 0.f, 0.f, 0.f};
        f32x4 o[2][4];
#pragma unroll
        for (int ct = 0; ct < 4; ++ct) {
            bf16x8 pb = __builtin_bit_cast(bf16x8,
                *(const uint4*)&sVT[((w << 6) + ct * 16 + l15) * TP + (q << 3)]);
            o[0][ct] = __builtin_amdgcn_mfma_f32_16x16x32_bf16(pa0, pb, z, 0, 0, 0);
            o[1][ct] = __builtin_amdgcn_mfma_f32_16x16x32_bf16(pa1, pb, z, 0, 0, 0);
        }
#pragma unroll
        for (int rt = 0; rt < 2; ++rt)
#pragma unroll
            for (int j = 0; j < 4; ++j) {
                int t = rt * 16 + (q << 2) + j;
                if (t < TT) {
                    int cnt = c_CNT[t], off = c_OFF[t];
                    float rs = (cnt == 0) ? 20.0f : s_simE[off];
#pragma unroll
                    for (int jj = 1; jj < 4; ++jj)
                        if (jj < cnt) rs += s_simE[off + jj];
                    float iv = __builtin_amdgcn_rcpf(rs);
                    float* op = outg + base + (size_t)t * CC + (w << 6) + l15;
#pragma unroll
                    for (int ct = 0; ct < 4; ++ct)
                        op[ct * 16] = o[rt][ct][j] * iv;
                }
            }
    }
}

extern "C" void kernel_launch(void* const* d_in, const int* in_sizes, int n_in,
                              void* d_out, int out_size, void* d_ws, size_t ws_size,
                              hipStream_t stream) {
    const float* feat1 = (const float*)d_in[0];
    const float* feat2 = (const float*)d_in[1];
    const float* Wq    = (const float*)d_in[2];
    const float* Wk    = (const float*)d_in[3];
    const float* Wv    = (const float*)d_in[4];
    uint16_t* mqkT = (uint16_t*)d_ws;          // 128 KB
    uint16_t* wvb  = mqkT + CC * CC;           // 128 KB
    uint16_t* BqS  = wvb  + CC * CC;           // 128 KB (swizzled)
    uint16_t* BvS  = BqS  + CC * CC;           // 128 KB (swizzled)

    prep1_kernel<<<CC, CC, 0, stream>>>(Wq, Wk, Wv, mqkT, wvb);
    prep2_kernel<<<64, NT, 0, stream>>>(mqkT, wvb, BqS, BvS);
    attn_main<<<NBATCH, NT, 0, stream>>>(feat1, feat2, BqS, BvS, (float*)d_out);
}